// Round 7
// baseline (582.566 us; speedup 1.0000x reference)
//
#include <hip/hip_runtime.h>
#include <hip/hip_bf16.h>
#include <cstddef>

// MHAttention forward, MI355X/gfx950.
// Dtype contract (R0-R3): inputs fp32 (toks, W*, b*; masks int32), OUTPUT fp32.
// Internals: bf16 MFMA fragments, fp32 accumulation.
// R6 -> R7: R6 NaN'd; prime suspect is the unverified 16x16x16bf16_1k builtin
// (layout errors give wrong-but-finite values; NaN implies garbage registers).
// R7 keeps R6's structure (S^T = K*Q^T orientation, split-K x2, vector mask
// loads, end-only reductions) but does PV through the R5-verified 16x16x32
// MFMA with a VECTORIZED LDS P round-trip (ds_write_b64 x2 + ds_read_b128 per
// q-subtile), plus explicit __syncthreads() around LDS region reuse.

typedef __bf16 bf16_8 __attribute__((ext_vector_type(8)));
typedef float f32x4 __attribute__((ext_vector_type(4)));
typedef short s16x4 __attribute__((ext_vector_type(4)));

#define HID 768
#define NHEADS 12
#define HD 64
#define BATCH 4
#define SEQ 2048
#define NEGBIG (-1e31f)

#define QSTR 72  // ldsQ row stride (elems): 144B rows, 16B aligned
#define PSTR 48  // ldsP row stride (elems): 96B rows, 16B aligned

static __device__ __forceinline__ f32x4 mfma16x16x32(bf16_8 a, bf16_8 b, f32x4 c) {
  return __builtin_amdgcn_mfma_f32_16x16x32_bf16(a, b, c, 0, 0, 0);
}

static __device__ __forceinline__ s16x4 pack_bf16x4(f32x4 p) {
  s16x4 o;
#pragma unroll
  for (int i = 0; i < 4; ++i) {
    __bf16 b = (__bf16)p[i];
    o[i] = __builtin_bit_cast(short, b);
  }
  return o;
}

static __device__ __forceinline__ bf16_8 cvt_a_frag(const float* p) {
  f32x4 af0 = *(const f32x4*)p;
  f32x4 af1 = *(const f32x4*)(p + 4);
  bf16_8 a;
  a[0] = (__bf16)af0[0]; a[1] = (__bf16)af0[1];
  a[2] = (__bf16)af0[2]; a[3] = (__bf16)af0[3];
  a[4] = (__bf16)af1[0]; a[5] = (__bf16)af1[1];
  a[6] = (__bf16)af1[2]; a[7] = (__bf16)af1[3];
  return a;
}

// ---------- mask -> additive kadd (0 or -1e31), fp32, global ----------
__global__ __launch_bounds__(256) void mask_kadd(const int* __restrict__ masks,
                                                 float* __restrict__ kaddG) {
  int i = blockIdx.x * 256 + threadIdx.x;
  kaddG[i] = masks[i] ? 0.0f : NEGBIG;
}

// ---------- 768x768 transpose + fp32->bf16 (W[k][n] -> Wt[n][k]) ----------
__global__ __launch_bounds__(256) void transpose768(const float* __restrict__ in,
                                                    __bf16* __restrict__ out) {
  __shared__ __bf16 tile[32][33];
  int bx = blockIdx.x * 32, by = blockIdx.y * 32;
  int tx = threadIdx.x, ty = threadIdx.y;  // block (32,8)
#pragma unroll
  for (int r = 0; r < 32; r += 8)
    tile[ty + r][tx] = (__bf16)in[(size_t)(by + ty + r) * HID + bx + tx];
  __syncthreads();
#pragma unroll
  for (int r = 0; r < 32; r += 8)
    out[(size_t)(bx + ty + r) * HID + by + tx] = tile[tx][ty + r];
}

// ---------- K+V projection fused: one wave -> 32 rows x 64 cols, both K and V ----------
__global__ __launch_bounds__(64) void proj_kv(const float* __restrict__ toks,
                                              const __bf16* __restrict__ WtK,
                                              const float* __restrict__ bk,
                                              const __bf16* __restrict__ WtV,
                                              const float* __restrict__ bv,
                                              __bf16* __restrict__ Kout,
                                              __bf16* __restrict__ Vtout,
                                              int head0, int hm) {
  int lane = threadIdx.x, l16 = lane & 15, quad = lane >> 4;
  int m0 = blockIdx.x * 32;
  int hl = blockIdx.y, h = head0 + hl;
  const float* arow0 = toks + (size_t)(m0 + l16) * HID + quad * 8;
  const float* arow1 = arow0 + (size_t)16 * HID;
  const __bf16* bKrow = WtK + (size_t)(h * 64 + l16) * HID + quad * 8;
  const __bf16* bVrow = WtV + (size_t)(h * 64 + l16) * HID + quad * 8;
  f32x4 zero = {0.f, 0.f, 0.f, 0.f};
  f32x4 aK[2][4], aV[2][4];
#pragma unroll
  for (int g = 0; g < 2; ++g)
#pragma unroll
    for (int t = 0; t < 4; ++t) { aK[g][t] = zero; aV[g][t] = zero; }
  for (int kk = 0; kk < HID; kk += 32) {
    bf16_8 a0 = cvt_a_frag(arow0 + kk);
    bf16_8 a1 = cvt_a_frag(arow1 + kk);
#pragma unroll
    for (int t = 0; t < 4; ++t) {
      bf16_8 bkf = *(const bf16_8*)(bKrow + (size_t)t * 16 * HID + kk);
      bf16_8 bvf = *(const bf16_8*)(bVrow + (size_t)t * 16 * HID + kk);
      aK[0][t] = mfma16x16x32(a0, bkf, aK[0][t]);
      aK[1][t] = mfma16x16x32(a1, bkf, aK[1][t]);
      aV[0][t] = mfma16x16x32(a0, bvf, aV[0][t]);
      aV[1][t] = mfma16x16x32(a1, bvf, aV[1][t]);
    }
  }
#pragma unroll
  for (int g = 0; g < 2; ++g)
#pragma unroll
    for (int t = 0; t < 4; ++t) {
      int d = t * 16 + l16;
      float bnK = bk[h * 64 + d];
      float bnV = bv[h * 64 + d];
#pragma unroll
      for (int r = 0; r < 4; ++r) {
        int m = m0 + g * 16 + quad * 4 + r;
        int b = m >> 11;
        int s = m & (SEQ - 1);
        Kout[(((size_t)b * hm + hl) * SEQ + s) * HD + d] = (__bf16)(aK[g][t][r] + bnK);
        Vtout[(((size_t)b * hm + hl) * HD + d) * SEQ + s] = (__bf16)(aV[g][t][r] + bnV);
      }
    }
}

// ---------- fused Q-proj + flash attention ----------
// Block = 128 threads (2 waves), split-K x2: wave w handles keys [w*1024, +1024)
// for a 32-query tile (2 x 16-q subtiles sharing K frags). S^T = K*Q^T so P
// exits QK with lane holding P[q=l16][key=quad*4+r] -> ONE ds_write_b64 per
// 16-key block, read back as the 16x16x32 A-frag. Merge partials via LDS once.
__global__ __launch_bounds__(128, 4) void attn_fused(const float* __restrict__ toks,
                                                     const __bf16* __restrict__ WtQ,
                                                     const float* __restrict__ bq,
                                                     const __bf16* __restrict__ Kbuf,
                                                     const __bf16* __restrict__ Vtbuf,
                                                     const float* __restrict__ kaddG,
                                                     float* __restrict__ out,
                                                     int head0, int hm) {
  __shared__ __align__(16) char ldsraw[9216];  // ldsQ phase -> ldsP phase -> merge
  int tid = threadIdx.x;
  int wave = tid >> 6, lane = tid & 63;
  int l16 = lane & 15, quad = lane >> 4;
  int bz = blockIdx.z, hl = blockIdx.y, h = head0 + hl;
  int q0 = blockIdx.x * 32;
  const float* kb = kaddG + (size_t)bz * SEQ;
  f32x4 zero = {0.f, 0.f, 0.f, 0.f};
  __bf16* ldsQ = (__bf16*)ldsraw + (size_t)wave * (2 * 16 * QSTR);

  // --- Q projection (each wave computes its own copy; both subtiles) ---
#pragma unroll
  for (int qt = 0; qt < 2; ++qt) {
    const float* arow = toks + ((size_t)bz * SEQ + q0 + qt * 16 + l16) * HID + quad * 8;
    const __bf16* brow = WtQ + (size_t)(h * 64 + l16) * HID + quad * 8;
    f32x4 qa[4] = {zero, zero, zero, zero};
    for (int kk = 0; kk < HID; kk += 32) {
      bf16_8 a = cvt_a_frag(arow + kk);
#pragma unroll
      for (int t = 0; t < 4; ++t)
        qa[t] = mfma16x16x32(a, *(const bf16_8*)(brow + (size_t)t * 16 * HID + kk), qa[t]);
    }
#pragma unroll
    for (int t = 0; t < 4; ++t) {
      float bn = bq[h * 64 + t * 16 + l16];
#pragma unroll
      for (int r = 0; r < 4; ++r)
        ldsQ[qt * 16 * QSTR + (quad * 4 + r) * QSTR + t * 16 + l16] = (__bf16)(qa[t][r] + bn);
    }
  }
  __builtin_amdgcn_wave_barrier();
  // Q frags: lane holds Q[q=l16][d=quad*8+j] — B-operand of S^T = K*Q^T.
  bf16_8 aq[2][2];
#pragma unroll
  for (int qt = 0; qt < 2; ++qt) {
    aq[qt][0] = *(const bf16_8*)(&ldsQ[qt * 16 * QSTR + l16 * QSTR + quad * 8]);
    aq[qt][1] = *(const bf16_8*)(&ldsQ[qt * 16 * QSTR + l16 * QSTR + 32 + quad * 8]);
  }
  // query-row activity (q = l16 per subtile): 1 -> normal, 0 -> all-zero logits
  float actq[2];
  actq[0] = (kb[q0 + l16] == 0.0f) ? 1.0f : 0.0f;
  actq[1] = (kb[q0 + 16 + l16] == 0.0f) ? 1.0f : 0.0f;
  __syncthreads();  // ldsQ fully consumed by BOTH waves before ldsP aliases it

  __bf16* ldsP = (__bf16*)ldsraw + (size_t)wave * (2 * 16 * PSTR);  // 6144B total

  const __bf16* Kb = Kbuf + ((size_t)bz * hm + hl) * SEQ * HD;
  const __bf16* Vb = Vtbuf + ((size_t)bz * hm + hl) * HD * SEQ;
  float lsum[2] = {0.f, 0.f};
  f32x4 acc[2][4];
#pragma unroll
  for (int qt = 0; qt < 2; ++qt)
#pragma unroll
    for (int dt = 0; dt < 4; ++dt) acc[qt][dt] = zero;

  const int ks = wave * (SEQ / 2);
  for (int kt = 0; kt < (SEQ / 2) / 32; ++kt) {
    int j0 = ks + kt * 32;
    // K A-frags: lane holds K[key=j0+blk*16+l16][d=quad*8+j (+32)]
    bf16_8 kf[2][2];
#pragma unroll
    for (int blk = 0; blk < 2; ++blk) {
      const __bf16* kp = Kb + (size_t)(j0 + blk * 16 + l16) * HD + quad * 8;
      kf[blk][0] = *(const bf16_8*)(kp);
      kf[blk][1] = *(const bf16_8*)(kp + 32);
    }
    // mask constants: key = j0 + blk*16 + quad*4 + r
    f32x4 ck[2];
    ck[0] = *(const f32x4*)(kb + j0 + quad * 4);
    ck[1] = *(const f32x4*)(kb + j0 + 16 + quad * 4);
#pragma unroll
    for (int qt = 0; qt < 2; ++qt) {
      // S^T tiles: lane holds S^T[key=blk*16+quad*4+r][q=l16]
      f32x4 st[2];
#pragma unroll
      for (int blk = 0; blk < 2; ++blk)
        st[blk] = mfma16x16x32(kf[blk][1], aq[qt][1],
                               mfma16x16x32(kf[blk][0], aq[qt][0], zero));
      __bf16* ldsPq = ldsP + (size_t)qt * 16 * PSTR;
#pragma unroll
      for (int blk = 0; blk < 2; ++blk) {
        f32x4 p;
#pragma unroll
        for (int r = 0; r < 4; ++r) {
          // masked key: fma -> -1e31, exp -> 0. inactive q: actq=0 -> logit 0.
          float v = actq[qt] * fmaf(st[blk][r], 0.125f, ck[blk][r]);
          p[r] = __expf(v);
        }
        lsum[qt] += p[0] + p[1] + p[2] + p[3];
        // P[q=l16][key=blk*16+quad*4 .. +4] -> one b64 store
        *(s16x4*)(&ldsPq[l16 * PSTR + blk * 16 + quad * 4]) = pack_bf16x4(p);
      }
      __builtin_amdgcn_wave_barrier();
      // A-frag for PV (16x16x32): row q = l16, k = local key = quad*8+j
      bf16_8 ap = *(const bf16_8*)(&ldsPq[l16 * PSTR + quad * 8]);
#pragma unroll
      for (int dt = 0; dt < 4; ++dt) {
        // V B-frag: Vt[d][key], d = dt*16+l16, key = j0+quad*8 (contiguous)
        bf16_8 bv = *(const bf16_8*)(Vb + (size_t)(dt * 16 + l16) * SEQ + j0 + quad * 8);
        acc[qt][dt] = mfma16x16x32(ap, bv, acc[qt][dt]);
      }
      __builtin_amdgcn_wave_barrier();
    }
  }

  // --- split-K merge via LDS (region reuse is safe: barrier first) ---
  __syncthreads();
  float* mA = (float*)ldsraw;                   // [2][4][64] x f32x4 = 8192B
  float* mL = (float*)ldsraw + 2 * 4 * 64 * 4;  // [2][64] = 512B
  if (wave == 1) {
#pragma unroll
    for (int qt = 0; qt < 2; ++qt) {
#pragma unroll
      for (int dt = 0; dt < 4; ++dt)
        *(f32x4*)&mA[((qt * 4 + dt) * 64 + lane) * 4] = acc[qt][dt];
      mL[qt * 64 + lane] = lsum[qt];
    }
  }
  __syncthreads();
  if (wave == 0) {
#pragma unroll
    for (int qt = 0; qt < 2; ++qt) {
#pragma unroll
      for (int dt = 0; dt < 4; ++dt)
        acc[qt][dt] += *(const f32x4*)&mA[((qt * 4 + dt) * 64 + lane) * 4];
      float s = lsum[qt] + mL[qt * 64 + lane];
      // total over all keys for q = l16 (sum across the 4 quads)
      s += __shfl_xor(s, 16);
      s += __shfl_xor(s, 32);
      float linv = 1.0f / s;
#pragma unroll
      for (int r = 0; r < 4; ++r) {
        float lr = __shfl(linv, quad * 4 + r);  // linv for q = quad*4+r
#pragma unroll
        for (int dt = 0; dt < 4; ++dt)
          out[((size_t)bz * SEQ + q0 + qt * 16 + quad * 4 + r) * HID + h * HD + dt * 16 + l16] =
              acc[qt][dt][r] * lr;
      }
    }
  }
}

extern "C" void kernel_launch(void* const* d_in, const int* in_sizes, int n_in,
                              void* d_out, int out_size, void* d_ws, size_t ws_size,
                              hipStream_t stream) {
  (void)in_sizes; (void)n_in; (void)out_size;
  const float* toks = (const float*)d_in[0];
  const int* masks = (const int*)d_in[1];
  const float* Wq = (const float*)d_in[2];
  const float* bq = (const float*)d_in[3];
  const float* Wk = (const float*)d_in[4];
  const float* bk = (const float*)d_in[5];
  const float* Wv = (const float*)d_in[6];
  const float* bv = (const float*)d_in[7];
  char* ws = (char*)d_ws;
  const size_t KADD_B = (size_t)BATCH * SEQ * 4;
  const size_t WT_B = (size_t)HID * HID * 2;
  const size_t KV_FULL_B = (size_t)BATCH * NHEADS * SEQ * HD * 2;
  const size_t KV_HEAD_B = (size_t)BATCH * SEQ * HD * 2;
  const size_t TIER_A_NEED = KADD_B + 3 * WT_B + 2 * KV_FULL_B;  // ~28.7 MB
  float* kaddG = (float*)(ws);
  __bf16* WtQ = (__bf16*)(ws + KADD_B + 0 * WT_B);
  __bf16* WtK = (__bf16*)(ws + KADD_B + 1 * WT_B);
  __bf16* WtV = (__bf16*)(ws + KADD_B + 2 * WT_B);
  float* outp = (float*)d_out;

  mask_kadd<<<BATCH * SEQ / 256, 256, 0, stream>>>(masks, kaddG);
  dim3 tgrid(HID / 32, HID / 32), tblk(32, 8);
  transpose768<<<tgrid, tblk, 0, stream>>>(Wq, WtQ);
  transpose768<<<tgrid, tblk, 0, stream>>>(Wk, WtK);
  transpose768<<<tgrid, tblk, 0, stream>>>(Wv, WtV);

  if (ws_size >= TIER_A_NEED) {
    __bf16* Kf = (__bf16*)(ws + KADD_B + 3 * WT_B);
    __bf16* Vtf = (__bf16*)(ws + KADD_B + 3 * WT_B + KV_FULL_B);
    dim3 pgrid(BATCH * SEQ / 32, NHEADS);
    proj_kv<<<pgrid, 64, 0, stream>>>(toks, WtK, bk, WtV, bv, Kf, Vtf, 0, NHEADS);
    dim3 agrid(SEQ / 32, NHEADS, BATCH);
    attn_fused<<<agrid, 128, 0, stream>>>(toks, WtQ, bq, Kf, Vtf, kaddG, outp, 0, NHEADS);
  } else {
    __bf16* Kh = (__bf16*)(ws + KADD_B + 3 * WT_B);
    __bf16* Vth = (__bf16*)(ws + KADD_B + 3 * WT_B + KV_HEAD_B);
    dim3 pgrid(BATCH * SEQ / 32, 1);
    dim3 agrid(SEQ / 32, 1, BATCH);
    for (int h = 0; h < NHEADS; ++h) {
      proj_kv<<<pgrid, 64, 0, stream>>>(toks, WtK, bk, WtV, bv, Kh, Vth, h, 1);
      attn_fused<<<agrid, 128, 0, stream>>>(toks, WtQ, bq, Kh, Vth, kaddG, outp, h, 1);
    }
  }
}

// Round 8
// 462.730 us; speedup vs baseline: 1.2590x; 1.2590x over previous
//
#include <hip/hip_runtime.h>
#include <hip/hip_bf16.h>
#include <cstddef>

// MHAttention forward, MI355X/gfx950.
// Dtype contract (R0-R3): inputs fp32 (toks, W*, b*; masks int32), OUTPUT fp32.
// Internals: bf16 MFMA fragments, fp32 accumulation.
// R7 -> R8 post-mortem: R7's per-qt wave_barriers (4 fences/kt) halved the
// schedulable window and blocked cross-iteration load hoisting; PSTR=48 gave
// 4-way LDS bank conflicts. R8: single-wave blocks (R5 grid), ZERO fences
// (same-wave DS ordering via may-alias deps), explicit register prefetch of
// K-frags+mask for kt+1, V-frags loaded at body top, PSTR=40 (2-way = free).
// S^T = K*Q^T orientation with b64 P stores (R7-verified lane mappings).

typedef __bf16 bf16_8 __attribute__((ext_vector_type(8)));
typedef float f32x4 __attribute__((ext_vector_type(4)));
typedef short s16x4 __attribute__((ext_vector_type(4)));

#define HID 768
#define NHEADS 12
#define HD 64
#define BATCH 4
#define SEQ 2048
#define NEGBIG (-1e31f)

#define QSTR 72  // ldsQ row stride (elems): 144B rows; 36 dwords -> 2-way only
#define PSTR 40  // ldsP row stride (elems):  80B rows; 20 dwords -> 2-way only

static __device__ __forceinline__ f32x4 mfma16x16x32(bf16_8 a, bf16_8 b, f32x4 c) {
  return __builtin_amdgcn_mfma_f32_16x16x32_bf16(a, b, c, 0, 0, 0);
}

static __device__ __forceinline__ s16x4 pack_bf16x4(f32x4 p) {
  s16x4 o;
#pragma unroll
  for (int i = 0; i < 4; ++i) {
    __bf16 b = (__bf16)p[i];
    o[i] = __builtin_bit_cast(short, b);
  }
  return o;
}

static __device__ __forceinline__ bf16_8 cvt_a_frag(const float* p) {
  f32x4 af0 = *(const f32x4*)p;
  f32x4 af1 = *(const f32x4*)(p + 4);
  bf16_8 a;
  a[0] = (__bf16)af0[0]; a[1] = (__bf16)af0[1];
  a[2] = (__bf16)af0[2]; a[3] = (__bf16)af0[3];
  a[4] = (__bf16)af1[0]; a[5] = (__bf16)af1[1];
  a[6] = (__bf16)af1[2]; a[7] = (__bf16)af1[3];
  return a;
}

// ---------- mask -> additive kadd (0 or -1e31), fp32, global ----------
__global__ __launch_bounds__(256) void mask_kadd(const int* __restrict__ masks,
                                                 float* __restrict__ kaddG) {
  int i = blockIdx.x * 256 + threadIdx.x;
  kaddG[i] = masks[i] ? 0.0f : NEGBIG;
}

// ---------- 3x 768x768 transpose + fp32->bf16, one launch (z picks matrix) ----------
__global__ __launch_bounds__(256) void transpose768x3(const float* __restrict__ Wq,
                                                      const float* __restrict__ Wk,
                                                      const float* __restrict__ Wv,
                                                      __bf16* __restrict__ WtBase) {
  const float* in = blockIdx.z == 0 ? Wq : (blockIdx.z == 1 ? Wk : Wv);
  __bf16* out = WtBase + (size_t)blockIdx.z * HID * HID;
  __shared__ __bf16 tile[32][33];
  int bx = blockIdx.x * 32, by = blockIdx.y * 32;
  int tx = threadIdx.x, ty = threadIdx.y;  // block (32,8)
#pragma unroll
  for (int r = 0; r < 32; r += 8)
    tile[ty + r][tx] = (__bf16)in[(size_t)(by + ty + r) * HID + bx + tx];
  __syncthreads();
#pragma unroll
  for (int r = 0; r < 32; r += 8)
    out[(size_t)(bx + ty + r) * HID + by + tx] = tile[tx][ty + r];
}

// ---------- K+V projection fused: one wave -> 32 rows x 64 cols, both K and V ----------
__global__ __launch_bounds__(64) void proj_kv(const float* __restrict__ toks,
                                              const __bf16* __restrict__ WtK,
                                              const float* __restrict__ bk,
                                              const __bf16* __restrict__ WtV,
                                              const float* __restrict__ bv,
                                              __bf16* __restrict__ Kout,
                                              __bf16* __restrict__ Vtout,
                                              int head0, int hm) {
  int lane = threadIdx.x, l16 = lane & 15, quad = lane >> 4;
  int m0 = blockIdx.x * 32;
  int hl = blockIdx.y, h = head0 + hl;
  const float* arow0 = toks + (size_t)(m0 + l16) * HID + quad * 8;
  const float* arow1 = arow0 + (size_t)16 * HID;
  const __bf16* bKrow = WtK + (size_t)(h * 64 + l16) * HID + quad * 8;
  const __bf16* bVrow = WtV + (size_t)(h * 64 + l16) * HID + quad * 8;
  f32x4 zero = {0.f, 0.f, 0.f, 0.f};
  f32x4 aK[2][4], aV[2][4];
#pragma unroll
  for (int g = 0; g < 2; ++g)
#pragma unroll
    for (int t = 0; t < 4; ++t) { aK[g][t] = zero; aV[g][t] = zero; }
  for (int kk = 0; kk < HID; kk += 32) {
    bf16_8 a0 = cvt_a_frag(arow0 + kk);
    bf16_8 a1 = cvt_a_frag(arow1 + kk);
#pragma unroll
    for (int t = 0; t < 4; ++t) {
      bf16_8 bkf = *(const bf16_8*)(bKrow + (size_t)t * 16 * HID + kk);
      bf16_8 bvf = *(const bf16_8*)(bVrow + (size_t)t * 16 * HID + kk);
      aK[0][t] = mfma16x16x32(a0, bkf, aK[0][t]);
      aK[1][t] = mfma16x16x32(a1, bkf, aK[1][t]);
      aV[0][t] = mfma16x16x32(a0, bvf, aV[0][t]);
      aV[1][t] = mfma16x16x32(a1, bvf, aV[1][t]);
    }
  }
#pragma unroll
  for (int g = 0; g < 2; ++g)
#pragma unroll
    for (int t = 0; t < 4; ++t) {
      int d = t * 16 + l16;
      float bnK = bk[h * 64 + d];
      float bnV = bv[h * 64 + d];
#pragma unroll
      for (int r = 0; r < 4; ++r) {
        int m = m0 + g * 16 + quad * 4 + r;
        int b = m >> 11;
        int s = m & (SEQ - 1);
        Kout[(((size_t)b * hm + hl) * SEQ + s) * HD + d] = (__bf16)(aK[g][t][r] + bnK);
        Vtout[(((size_t)b * hm + hl) * HD + d) * SEQ + s] = (__bf16)(aV[g][t][r] + bnV);
      }
    }
}

// ---------- fused Q-proj + flash attention ----------
// ONE wave per (b, h, 32-query tile); 2 x 16-q subtiles share K/V frags.
// S^T = K*Q^T: lane exits QK holding P[q=l16][key=quad*4+r] -> one ds_write_b64
// per 16-key blk, read back b128 as the 16x16x32 PV A-frag. No barriers anywhere:
// single-wave block, DS ordering guaranteed by may-alias memory deps + in-order DS.
// K-frags and mask vector for kt+1 are register-prefetched; V-frags for kt load
// at body top (used at bottom).
__global__ __launch_bounds__(64) void attn_fused(const float* __restrict__ toks,
                                                 const __bf16* __restrict__ WtQ,
                                                 const float* __restrict__ bq,
                                                 const __bf16* __restrict__ Kbuf,
                                                 const __bf16* __restrict__ Vtbuf,
                                                 const float* __restrict__ kaddG,
                                                 float* __restrict__ out,
                                                 int head0, int hm) {
  __shared__ __align__(16) __bf16 ldsQ[2][16 * QSTR];  // 4608 B
  __shared__ __align__(16) __bf16 ldsP[2][16 * PSTR];  // 2560 B
  int lane = threadIdx.x, l16 = lane & 15, quad = lane >> 4;
  int bz = blockIdx.z, hl = blockIdx.y, h = head0 + hl;
  int q0 = blockIdx.x * 32;
  const float* kb = kaddG + (size_t)bz * SEQ;
  f32x4 zero = {0.f, 0.f, 0.f, 0.f};

  // --- Q projection: both 16-row subtiles ---
#pragma unroll
  for (int qt = 0; qt < 2; ++qt) {
    const float* arow = toks + ((size_t)bz * SEQ + q0 + qt * 16 + l16) * HID + quad * 8;
    const __bf16* brow = WtQ + (size_t)(h * 64 + l16) * HID + quad * 8;
    f32x4 qa[4] = {zero, zero, zero, zero};
    for (int kk = 0; kk < HID; kk += 32) {
      bf16_8 a = cvt_a_frag(arow + kk);
#pragma unroll
      for (int t = 0; t < 4; ++t)
        qa[t] = mfma16x16x32(a, *(const bf16_8*)(brow + (size_t)t * 16 * HID + kk), qa[t]);
    }
#pragma unroll
    for (int t = 0; t < 4; ++t) {
      float bn = bq[h * 64 + t * 16 + l16];
#pragma unroll
      for (int r = 0; r < 4; ++r)
        ldsQ[qt][(quad * 4 + r) * QSTR + t * 16 + l16] = (__bf16)(qa[t][r] + bn);
    }
  }
  // Q frags (RAW dep on the stores above orders this): lane holds Q[q=l16][d=quad*8+j]
  bf16_8 aq[2][2];
#pragma unroll
  for (int qt = 0; qt < 2; ++qt) {
    aq[qt][0] = *(const bf16_8*)(&ldsQ[qt][l16 * QSTR + quad * 8]);
    aq[qt][1] = *(const bf16_8*)(&ldsQ[qt][l16 * QSTR + 32 + quad * 8]);
  }
  // query-row activity (q = l16 per subtile): 1 -> normal, 0 -> all-zero logits (= ref)
  float actq[2];
  actq[0] = (kb[q0 + l16] == 0.0f) ? 1.0f : 0.0f;
  actq[1] = (kb[q0 + 16 + l16] == 0.0f) ? 1.0f : 0.0f;

  const __bf16* Kb = Kbuf + ((size_t)bz * hm + hl) * SEQ * HD;
  const __bf16* Vb = Vtbuf + ((size_t)bz * hm + hl) * HD * SEQ;
  float lsum[2] = {0.f, 0.f};
  f32x4 acc[2][4];
#pragma unroll
  for (int qt = 0; qt < 2; ++qt)
#pragma unroll
    for (int dt = 0; dt < 4; ++dt) acc[qt][dt] = zero;

  const int NKT = SEQ / 32;
  // preload kt=0: K A-frags (lane holds K[key=blk*16+l16][d=quad*8+j (+32)]) + mask vec
  bf16_8 kf[2][2];
  f32x4 ck[2];
  {
    const __bf16* kp0 = Kb + (size_t)l16 * HD + quad * 8;
    const __bf16* kp1 = Kb + (size_t)(16 + l16) * HD + quad * 8;
    kf[0][0] = *(const bf16_8*)kp0; kf[0][1] = *(const bf16_8*)(kp0 + 32);
    kf[1][0] = *(const bf16_8*)kp1; kf[1][1] = *(const bf16_8*)(kp1 + 32);
    ck[0] = *(const f32x4*)(kb + quad * 4);
    ck[1] = *(const f32x4*)(kb + 16 + quad * 4);
  }
  for (int kt = 0; kt < NKT; ++kt) {
    int j0 = kt * 32;
    int jn = (kt + 1 < NKT) ? j0 + 32 : 0;  // wrap: avoids OOB, values unused
    // V B-frags for THIS iteration (used at body bottom -> latency hidden)
    bf16_8 vf[4];
#pragma unroll
    for (int dt = 0; dt < 4; ++dt)
      vf[dt] = *(const bf16_8*)(Vb + (size_t)(dt * 16 + l16) * SEQ + j0 + quad * 8);
    // prefetch NEXT iteration's K frags + mask vec
    bf16_8 kfn[2][2];
    f32x4 ckn[2];
    {
      const __bf16* kp0 = Kb + (size_t)(jn + l16) * HD + quad * 8;
      const __bf16* kp1 = Kb + (size_t)(jn + 16 + l16) * HD + quad * 8;
      kfn[0][0] = *(const bf16_8*)kp0; kfn[0][1] = *(const bf16_8*)(kp0 + 32);
      kfn[1][0] = *(const bf16_8*)kp1; kfn[1][1] = *(const bf16_8*)(kp1 + 32);
      ckn[0] = *(const f32x4*)(kb + jn + quad * 4);
      ckn[1] = *(const f32x4*)(kb + jn + 16 + quad * 4);
    }
    // QK -> exp -> pack -> P store (both subtiles)
#pragma unroll
    for (int qt = 0; qt < 2; ++qt) {
#pragma unroll
      for (int blk = 0; blk < 2; ++blk) {
        f32x4 st = mfma16x16x32(kf[blk][1], aq[qt][1],
                                mfma16x16x32(kf[blk][0], aq[qt][0], zero));
        f32x4 p;
#pragma unroll
        for (int r = 0; r < 4; ++r) {
          // masked key: fma -> -1e31, exp -> 0. inactive q: actq=0 -> logit 0.
          float v = actq[qt] * fmaf(st[r], 0.125f, ck[blk][r]);
          p[r] = __expf(v);
        }
        lsum[qt] += p[0] + p[1] + p[2] + p[3];
        // P[q=l16][key=blk*16+quad*4 .. +4] -> one b64 store
        *(s16x4*)(&ldsP[qt][l16 * PSTR + blk * 16 + quad * 4]) = pack_bf16x4(p);
      }
    }
    // PV: A-frag = P row q=l16, k=quad*8+j (RAW dep on stores above orders this)
#pragma unroll
    for (int qt = 0; qt < 2; ++qt) {
      bf16_8 ap = *(const bf16_8*)(&ldsP[qt][l16 * PSTR + quad * 8]);
#pragma unroll
      for (int dt = 0; dt < 4; ++dt)
        acc[qt][dt] = mfma16x16x32(ap, vf[dt], acc[qt][dt]);
    }
    kf[0][0] = kfn[0][0]; kf[0][1] = kfn[0][1];
    kf[1][0] = kfn[1][0]; kf[1][1] = kfn[1][1];
    ck[0] = ckn[0]; ck[1] = ckn[1];
  }

  // denominator: per-lane partials live at (q=l16, key-quad=quad) -> sum quads
#pragma unroll
  for (int qt = 0; qt < 2; ++qt) {
    float s = lsum[qt];
    s += __shfl_xor(s, 16);
    s += __shfl_xor(s, 32);
    float linv = 1.0f / s;
#pragma unroll
    for (int r = 0; r < 4; ++r) {
      float lr = __shfl(linv, quad * 4 + r);  // linv for q = quad*4+r
#pragma unroll
      for (int dt = 0; dt < 4; ++dt)
        out[((size_t)bz * SEQ + q0 + qt * 16 + quad * 4 + r) * HID + h * HD + dt * 16 + l16] =
            acc[qt][dt][r] * lr;
    }
  }
}

extern "C" void kernel_launch(void* const* d_in, const int* in_sizes, int n_in,
                              void* d_out, int out_size, void* d_ws, size_t ws_size,
                              hipStream_t stream) {
  (void)in_sizes; (void)n_in; (void)out_size;
  const float* toks = (const float*)d_in[0];
  const int* masks = (const int*)d_in[1];
  const float* Wq = (const float*)d_in[2];
  const float* bq = (const float*)d_in[3];
  const float* Wk = (const float*)d_in[4];
  const float* bk = (const float*)d_in[5];
  const float* Wv = (const float*)d_in[6];
  const float* bv = (const float*)d_in[7];
  char* ws = (char*)d_ws;
  const size_t KADD_B = (size_t)BATCH * SEQ * 4;
  const size_t WT_B = (size_t)HID * HID * 2;
  const size_t KV_FULL_B = (size_t)BATCH * NHEADS * SEQ * HD * 2;
  const size_t KV_HEAD_B = (size_t)BATCH * SEQ * HD * 2;
  const size_t TIER_A_NEED = KADD_B + 3 * WT_B + 2 * KV_FULL_B;  // ~28.7 MB
  float* kaddG = (float*)(ws);
  __bf16* WtQ = (__bf16*)(ws + KADD_B + 0 * WT_B);
  __bf16* WtK = (__bf16*)(ws + KADD_B + 1 * WT_B);
  __bf16* WtV = (__bf16*)(ws + KADD_B + 2 * WT_B);
  float* outp = (float*)d_out;

  mask_kadd<<<BATCH * SEQ / 256, 256, 0, stream>>>(masks, kaddG);
  dim3 tgrid(HID / 32, HID / 32, 3), tblk(32, 8);
  transpose768x3<<<tgrid, tblk, 0, stream>>>(Wq, Wk, Wv, WtQ);

  if (ws_size >= TIER_A_NEED) {
    __bf16* Kf = (__bf16*)(ws + KADD_B + 3 * WT_B);
    __bf16* Vtf = (__bf16*)(ws + KADD_B + 3 * WT_B + KV_FULL_B);
    dim3 pgrid(BATCH * SEQ / 32, NHEADS);
    proj_kv<<<pgrid, 64, 0, stream>>>(toks, WtK, bk, WtV, bv, Kf, Vtf, 0, NHEADS);
    dim3 agrid(SEQ / 32, NHEADS, BATCH);
    attn_fused<<<agrid, 64, 0, stream>>>(toks, WtQ, bq, Kf, Vtf, kaddG, outp, 0, NHEADS);
  } else {
    __bf16* Kh = (__bf16*)(ws + KADD_B + 3 * WT_B);
    __bf16* Vth = (__bf16*)(ws + KADD_B + 3 * WT_B + KV_HEAD_B);
    dim3 pgrid(BATCH * SEQ / 32, 1);
    dim3 agrid(SEQ / 32, 1, BATCH);
    for (int h = 0; h < NHEADS; ++h) {
      proj_kv<<<pgrid, 64, 0, stream>>>(toks, WtK, bk, WtV, bv, Kh, Vth, h, 1);
      attn_fused<<<agrid, 64, 0, stream>>>(toks, WtQ, bq, Kh, Vth, kaddG, outp, h, 1);
    }
  }
}